// Round 10
// baseline (218.751 us; speedup 1.0000x reference)
//
#include <hip/hip_runtime.h>
#include <hip/hip_bf16.h>
#include <stdint.h>

#define NHEADS 8
#define INDIM 512
#define EMB 512
#define BSZ 4
#define NQS 2048
#define GS 2048

// 0.125 * log2(e): folded into W_query so attention exp is a bare 2^x
#define ALPHA_F 0.18033688011112042f

#if __has_builtin(__builtin_amdgcn_exp2f)
#define EXP2(x) __builtin_amdgcn_exp2f(x)
#else
#define EXP2(x) __expf((x)*0.69314718056f)
#endif

typedef short bf16x8 __attribute__((ext_vector_type(8)));
typedef float f32x4 __attribute__((ext_vector_type(4)));
typedef float f32x16 __attribute__((ext_vector_type(16)));
typedef unsigned int u32x4 __attribute__((ext_vector_type(4)));

static __device__ __forceinline__ unsigned short f2bf(float f) {
  unsigned int u = __builtin_bit_cast(unsigned int, f);
  unsigned int rounding = 0x7FFFu + ((u >> 16) & 1u);
  u += rounding;
  return (unsigned short)(u >> 16);
}

typedef __attribute__((address_space(3))) void lds_void;
typedef __attribute__((address_space(1))) const void gm_void;
static __device__ __forceinline__ void gll16(const void* g, void* s) {
  __builtin_amdgcn_global_load_lds((gm_void*)g, (lds_void*)s, 16, 0, 0);
}

// ---------------- fused prep: cvt q,h + pack weights + bit-pack mask ----------------
__global__ void k_prep(const float4* __restrict__ q, const float4* __restrict__ h,
                       const void* __restrict__ mask,
                       const float* __restrict__ wq, const float* __restrict__ wk,
                       const float* __restrict__ wv, const float* __restrict__ wo,
                       ushort4* __restrict__ qb, ushort4* __restrict__ hb,
                       unsigned short* __restrict__ wqt, unsigned short* __restrict__ wkvt,
                       unsigned short* __restrict__ wot, unsigned short* __restrict__ maskB16) {
  int blk = blockIdx.x, t = threadIdx.x;
  if (blk < 2048) {
    const float4* src = blk < 1024 ? q : h;
    ushort4* dst = blk < 1024 ? qb : hb;
    int base = (blk & 1023) * 256 + t;
#pragma unroll
    for (int i = 0; i < 4; i++) {
      int idx = base + i * 262144;
      float4 v = src[idx];
      ushort4 o;
      o.x = f2bf(v.x); o.y = f2bf(v.y); o.z = f2bf(v.z); o.w = f2bf(v.w);
      dst[idx] = o;
    }
  } else if (blk < 3072) {
    const unsigned int* m32h = (const unsigned int*)mask;
    bool bytes = __ballot(m32h[t & 63] > 1u) != 0ull;
    int base = (blk - 2048) * 256 + t;
#pragma unroll
    for (int i = 0; i < 4; i++) {
      int widx = base + i * 262144;
      unsigned int bits = 0;
      if (bytes) {
        const uchar4* p = (const uchar4*)((const unsigned char*)mask + (size_t)widx * 16);
#pragma unroll
        for (int j = 0; j < 4; j++) {
          uchar4 v = p[j];
          bits |= ((v.x ? 1u : 0u) << (4 * j)) | ((v.y ? 1u : 0u) << (4 * j + 1)) |
                  ((v.z ? 1u : 0u) << (4 * j + 2)) | ((v.w ? 1u : 0u) << (4 * j + 3));
        }
      } else {
        const int4* p = (const int4*)((const int*)mask + (size_t)widx * 16);
#pragma unroll
        for (int j = 0; j < 4; j++) {
          int4 v = p[j];
          bits |= ((v.x ? 1u : 0u) << (4 * j)) | ((v.y ? 1u : 0u) << (4 * j + 1)) |
                  ((v.z ? 1u : 0u) << (4 * j + 2)) | ((v.w ? 1u : 0u) << (4 * j + 3));
        }
      }
      maskB16[widx] = (unsigned short)bits;
    }
  } else {
    int id = (blk - 3072) * 256 + t;
#pragma unroll
    for (int i = 0; i < 8; i++) {
      int e = id * 8 + i;
      int which = e >> 18, r = e & 262143;
      int k = r & 511, n = r >> 9;
      int hh = n >> 6, j = n & 63;
      if (which == 0) wqt[r] = f2bf(wq[hh * 32768 + k * 64 + j] * ALPHA_F);
      else if (which == 1) wkvt[r] = f2bf(wk[hh * 32768 + k * 64 + j]);
      else if (which == 2) wkvt[262144 + r] = f2bf(wv[hh * 32768 + k * 64 + j]);
      else wot[r] = f2bf(wo[k * 512 + n]);
    }
  }
}

// ---------------- out-proj GEMM (BM=64, BN=128, BK=64, counted prefetch) ----------------
template <int MODE>
__global__ __launch_bounds__(256) void k_gemm3(const unsigned short* __restrict__ A,
                                               const unsigned short* __restrict__ Bt,
                                               void* __restrict__ C, void* __restrict__ C2) {
  __shared__ unsigned short As[2][4096];
  __shared__ unsigned short Bs[2][8192];
  int m0 = blockIdx.x * 64, n0 = blockIdx.y * 128;
  int t = threadIdx.x;
  int w = t >> 6, l = t & 63, c = l & 15, lg = l >> 4;
  int wr = w >> 1, wc = w & 1;

  int rbA = t >> 7, kcc = (t >> 4) & 7, cc = t & 15;
  const unsigned short* aG = A + (size_t)(m0 + rbA * 16 + cc) * 512 + kcc * 8;
  const unsigned short* bG = Bt + (size_t)(n0 + rbA * 16 + cc) * 512 + kcc * 8;
  int ldsOff = w * 1024 + (t & 63) * 16;

  f32x4 acc[2][4];
#pragma unroll
  for (int mi = 0; mi < 2; mi++)
#pragma unroll
    for (int ni = 0; ni < 4; ni++) acc[mi][ni] = {0.f, 0.f, 0.f, 0.f};

  gll16(aG, (char*)As[0] + ldsOff);
  gll16(aG + 32 * 512, (char*)As[0] + ldsOff + 4096);
  gll16(bG, (char*)Bs[0] + ldsOff);
  gll16(bG + 32 * 512, (char*)Bs[0] + ldsOff + 4096);
  gll16(bG + 64 * 512, (char*)Bs[0] + ldsOff + 8192);
  gll16(bG + 96 * 512, (char*)Bs[0] + ldsOff + 12288);

  for (int kk = 0; kk < 8; kk++) {
    int cur = kk & 1;
    asm volatile("s_waitcnt vmcnt(0)" ::: "memory");
    __builtin_amdgcn_s_barrier();
    if (kk < 7) {
      int ko = (kk + 1) * 64;
      gll16(aG + ko, (char*)As[cur ^ 1] + ldsOff);
      gll16(aG + ko + 32 * 512, (char*)As[cur ^ 1] + ldsOff + 4096);
      gll16(bG + ko, (char*)Bs[cur ^ 1] + ldsOff);
      gll16(bG + ko + 32 * 512, (char*)Bs[cur ^ 1] + ldsOff + 4096);
      gll16(bG + ko + 64 * 512, (char*)Bs[cur ^ 1] + ldsOff + 8192);
      gll16(bG + ko + 96 * 512, (char*)Bs[cur ^ 1] + ldsOff + 12288);
    }
    bf16x8 af[2][2], bfr[4][2];
#pragma unroll
    for (int kc = 0; kc < 2; kc++) {
#pragma unroll
      for (int mi = 0; mi < 2; mi++)
        af[mi][kc] = *(const bf16x8*)((const char*)As[cur] + ((wr * 2 + mi) * 128 + (kc * 4 + lg) * 16 + c) * 16);
#pragma unroll
      for (int ni = 0; ni < 4; ni++)
        bfr[ni][kc] = *(const bf16x8*)((const char*)Bs[cur] + ((wc * 4 + ni) * 128 + (kc * 4 + lg) * 16 + c) * 16);
    }
#pragma unroll
    for (int kc = 0; kc < 2; kc++)
#pragma unroll
      for (int mi = 0; mi < 2; mi++)
#pragma unroll
        for (int ni = 0; ni < 4; ni++)
          acc[mi][ni] = __builtin_amdgcn_mfma_f32_16x16x32_bf16(af[mi][kc], bfr[ni][kc], acc[mi][ni], 0, 0, 0);
  }

#pragma unroll
  for (int mi = 0; mi < 2; mi++)
#pragma unroll
    for (int ni = 0; ni < 4; ni++) {
      int row = m0 + wr * 32 + mi * 16 + 4 * lg;
      int col = n0 + wc * 64 + ni * 16 + c;
#pragma unroll
      for (int r = 0; r < 4; r++)
        ((float*)C)[(size_t)(row + r) * 512 + col] = acc[mi][ni][r];
    }
}

// fused Q/K/V projection: grid (128, 12). y<4: Q -> Qp. y in [4,8): K -> Kp. [8,12): V -> Vt.
__global__ __launch_bounds__(256) void k_gemmQKV(const unsigned short* __restrict__ qb_,
                                                 const unsigned short* __restrict__ hb_,
                                                 const unsigned short* __restrict__ wqt,
                                                 const unsigned short* __restrict__ wkvt,
                                                 unsigned short* __restrict__ Qp,
                                                 unsigned short* __restrict__ Kp,
                                                 unsigned short* __restrict__ Vt) {
  __shared__ unsigned short As[2][4096];
  __shared__ unsigned short Bs[2][8192];
  int ny = blockIdx.y;
  const unsigned short* A = (ny < 4) ? qb_ : hb_;
  const unsigned short* Bt = (ny < 4) ? wqt : wkvt;
  int n0 = (ny < 4) ? ny * 128 : (ny - 4) * 128;
  int m0 = blockIdx.x * 64;
  int t = threadIdx.x;
  int w = t >> 6, l = t & 63, c = l & 15, lg = l >> 4;
  int wr = w >> 1, wc = w & 1;

  int rbA = t >> 7, kcc = (t >> 4) & 7, cc = t & 15;
  const unsigned short* aG = A + (size_t)(m0 + rbA * 16 + cc) * 512 + kcc * 8;
  const unsigned short* bG = Bt + (size_t)(n0 + rbA * 16 + cc) * 512 + kcc * 8;
  int ldsOff = w * 1024 + (t & 63) * 16;

  f32x4 acc[2][4];
#pragma unroll
  for (int mi = 0; mi < 2; mi++)
#pragma unroll
    for (int ni = 0; ni < 4; ni++) acc[mi][ni] = {0.f, 0.f, 0.f, 0.f};

  gll16(aG, (char*)As[0] + ldsOff);
  gll16(aG + 32 * 512, (char*)As[0] + ldsOff + 4096);
  gll16(bG, (char*)Bs[0] + ldsOff);
  gll16(bG + 32 * 512, (char*)Bs[0] + ldsOff + 4096);
  gll16(bG + 64 * 512, (char*)Bs[0] + ldsOff + 8192);
  gll16(bG + 96 * 512, (char*)Bs[0] + ldsOff + 12288);

  for (int kk = 0; kk < 8; kk++) {
    int cur = kk & 1;
    asm volatile("s_waitcnt vmcnt(0)" ::: "memory");
    __builtin_amdgcn_s_barrier();
    if (kk < 7) {
      int ko = (kk + 1) * 64;
      gll16(aG + ko, (char*)As[cur ^ 1] + ldsOff);
      gll16(aG + ko + 32 * 512, (char*)As[cur ^ 1] + ldsOff + 4096);
      gll16(bG + ko, (char*)Bs[cur ^ 1] + ldsOff);
      gll16(bG + ko + 32 * 512, (char*)Bs[cur ^ 1] + ldsOff + 4096);
      gll16(bG + ko + 64 * 512, (char*)Bs[cur ^ 1] + ldsOff + 8192);
      gll16(bG + ko + 96 * 512, (char*)Bs[cur ^ 1] + ldsOff + 12288);
    }
    bf16x8 af[2][2], bfr[4][2];
#pragma unroll
    for (int kc = 0; kc < 2; kc++) {
#pragma unroll
      for (int mi = 0; mi < 2; mi++)
        af[mi][kc] = *(const bf16x8*)((const char*)As[cur] + ((wr * 2 + mi) * 128 + (kc * 4 + lg) * 16 + c) * 16);
#pragma unroll
      for (int ni = 0; ni < 4; ni++)
        bfr[ni][kc] = *(const bf16x8*)((const char*)Bs[cur] + ((wc * 4 + ni) * 128 + (kc * 4 + lg) * 16 + c) * 16);
    }
#pragma unroll
    for (int kc = 0; kc < 2; kc++)
#pragma unroll
      for (int mi = 0; mi < 2; mi++)
#pragma unroll
        for (int ni = 0; ni < 4; ni++)
          acc[mi][ni] = __builtin_amdgcn_mfma_f32_16x16x32_bf16(af[mi][kc], bfr[ni][kc], acc[mi][ni], 0, 0, 0);
  }

#pragma unroll
  for (int mi = 0; mi < 2; mi++)
#pragma unroll
    for (int ni = 0; ni < 4; ni++) {
      int row = m0 + wr * 32 + mi * 16 + 4 * lg;
      int col = n0 + wc * 64 + ni * 16 + c;
      if (ny < 4) {
#pragma unroll
        for (int r = 0; r < 4; r++)
          Qp[(size_t)(row + r) * 512 + col] = f2bf(acc[mi][ni][r]);
      } else if (col < 512) {
#pragma unroll
        for (int r = 0; r < 4; r++)
          Kp[(size_t)(row + r) * 512 + col] = f2bf(acc[mi][ni][r]);
      } else {
        int col5 = col - 512, hd2 = col5 >> 6, vv = col5 & 63;
        int bb = row >> 11, g = row & 2047;
        ushort4 u;
        u.x = f2bf(acc[mi][ni][0]);
        u.y = f2bf(acc[mi][ni][1]);
        u.z = f2bf(acc[mi][ni][2]);
        u.w = f2bf(acc[mi][ni][3]);
        *(ushort4*)(Vt + (size_t)((bb * 8 + hd2) * 64 + vv) * GS + g) = u;
      }
    }
}

// ---------------- flash attention: ALL-REGISTER, 32x32x16 MFMA, zero LDS, zero barriers ----
// grid 512: fid = (bid&7)*64 + bid>>3 (XCD-bijective). qtile = fid&15 (128 q), bh = fid>>4.
// Each lane owns q = qtile*128 + w*32 + (l&31). Swapped operands:
//   S^T = K*Q^T  (A=K frag: row g=l&31, k=(l>>5)*8+j ; B=Q frag: col q, same k map)
//   C map (verified m74/m101): col = l&31, row = (r&3)+8*(r>>2)+4*(l>>5)
// P converted in-register via v_cvt_pk_bf16_f32 + v_permlane32_swap_b32 into PV B-fragments.
// K/V fragments loaded straight from global (L1/L2 serve reuse; K+V per (b,hd) = 512 KB, 4 bh/XCD).
__global__ __launch_bounds__(256, 2) void k_attn7(const unsigned short* __restrict__ Qp,
                                                  const unsigned short* __restrict__ Kp,
                                                  const unsigned short* __restrict__ Vt,
                                                  const unsigned short* __restrict__ maskB16,
                                                  unsigned short* __restrict__ Hd) {
  int bid = blockIdx.x;
  int fid = (bid & 7) * 64 + (bid >> 3);
  int qtile = fid & 15;
  int bh = fid >> 4;
  int b = bh >> 3, hd = bh & 7;

  int t = threadIdx.x;
  int w = t >> 6, l = t & 63;
  int lo = l & 31, hi = l >> 5;
  int hi4 = hi * 4;
  int q = qtile * 128 + w * 32 + lo;

  // Q B-fragments (4 k-steps of 16 over d=64)
  const unsigned short* qrow = Qp + (size_t)(b * NQS + q) * 512 + hd * 64 + hi * 8;
  bf16x8 qf[4];
#pragma unroll
  for (int s = 0; s < 4; s++) qf[s] = *(const bf16x8*)(qrow + s * 16);

  const unsigned short* krow = Kp + (size_t)(b * GS + lo) * 512 + hd * 64 + hi * 8;
  const unsigned short* vrow0 = Vt + (size_t)(bh * 64 + lo) * GS + hi * 8;
  const unsigned short* vrow1 = Vt + (size_t)(bh * 64 + 32 + lo) * GS + hi * 8;
  const unsigned long long* mrow = (const unsigned long long*)maskB16 + (size_t)(b * NQS + q) * 32;

  f32x16 o0, o1;
#pragma unroll
  for (int i = 0; i < 16; i++) { o0[i] = 0.f; o1[i] = 0.f; }
  float ls[4] = {0.f, 0.f, 0.f, 0.f};

  for (int kt = 0; kt < 32; kt++) {
    unsigned long long wm = mrow[kt];
#pragma unroll
    for (int g2 = 0; g2 < 2; g2++) {
      int gbase = kt * 64 + g2 * 32;
      // S^T = K * Q^T
      f32x16 sreg;
#pragma unroll
      for (int i = 0; i < 16; i++) sreg[i] = 0.f;
#pragma unroll
      for (int s = 0; s < 4; s++) {
        bf16x8 ka = *(const bf16x8*)(krow + (size_t)gbase * 512 + s * 16);
        sreg = __builtin_amdgcn_mfma_f32_32x32x16_bf16(ka, qf[s], sreg, 0, 0, 0);
      }
      // masked 2^s (lane-local: 16 g-rows for this lane's q)
      unsigned int mbits = (unsigned int)(wm >> (g2 * 32));
      float p[16];
#pragma unroll
      for (int r = 0; r < 16; r++) {
        float e = EXP2(sreg[r]);
        unsigned bit = (mbits >> ((r & 3) + 8 * (r >> 2) + hi4)) & 1u;
        p[r] = bit ? 0.f : e;
        ls[r & 3] += p[r];
      }
      // pack P -> bf16 PV B-fragments (cvt_pk + permlane32_swap; derivation in journal)
      unsigned int cw0, cw1, cw2, cw3, cw4, cw5, cw6, cw7;
      asm("v_cvt_pk_bf16_f32 %0, %1, %2" : "=v"(cw0) : "v"(p[0]), "v"(p[1]));
      asm("v_cvt_pk_bf16_f32 %0, %1, %2" : "=v"(cw1) : "v"(p[2]), "v"(p[3]));
      asm("v_cvt_pk_bf16_f32 %0, %1, %2" : "=v"(cw2) : "v"(p[4]), "v"(p[5]));
      asm("v_cvt_pk_bf16_f32 %0, %1, %2" : "=v"(cw3) : "v"(p[6]), "v"(p[7]));
      asm("v_cvt_pk_bf16_f32 %0, %1, %2" : "=v"(cw4) : "v"(p[8]), "v"(p[9]));
      asm("v_cvt_pk_bf16_f32 %0, %1, %2" : "=v"(cw5) : "v"(p[10]), "v"(p[11]));
      asm("v_cvt_pk_bf16_f32 %0, %1, %2" : "=v"(cw6) : "v"(p[12]), "v"(p[13]));
      asm("v_cvt_pk_bf16_f32 %0, %1, %2" : "=v"(cw7) : "v"(p[14]), "v"(p[15]));
      asm("v_permlane32_swap_b32 %0, %1" : "+v"(cw0), "+v"(cw2));
      asm("v_permlane32_swap_b32 %0, %1" : "+v"(cw1), "+v"(cw3));
      asm("v_permlane32_swap_b32 %0, %1" : "+v"(cw4), "+v"(cw6));
      asm("v_permlane32_swap_b32 %0, %1" : "+v"(cw5), "+v"(cw7));
      u32x4 pw0 = {cw0, cw1, cw2, cw3};
      u32x4 pw1 = {cw4, cw5, cw6, cw7};
      bf16x8 pb0 = __builtin_bit_cast(bf16x8, pw0);
      bf16x8 pb1 = __builtin_bit_cast(bf16x8, pw1);
      // O^T += V^T * P^T  (2 k-steps of 16 g)
      bf16x8 va00 = *(const bf16x8*)(vrow0 + gbase);
      bf16x8 va10 = *(const bf16x8*)(vrow1 + gbase);
      bf16x8 va01 = *(const bf16x8*)(vrow0 + gbase + 16);
      bf16x8 va11 = *(const bf16x8*)(vrow1 + gbase + 16);
      o0 = __builtin_amdgcn_mfma_f32_32x32x16_bf16(va00, pb0, o0, 0, 0, 0);
      o1 = __builtin_amdgcn_mfma_f32_32x32x16_bf16(va10, pb0, o1, 0, 0, 0);
      o0 = __builtin_amdgcn_mfma_f32_32x32x16_bf16(va01, pb1, o0, 0, 0, 0);
      o1 = __builtin_amdgcn_mfma_f32_32x32x16_bf16(va11, pb1, o1, 0, 0, 0);
    }
  }

  // epilogue: combine partner lane's l, normalize, store
  float lsum = (ls[0] + ls[1]) + (ls[2] + ls[3]);
  lsum += __shfl_xor(lsum, 32);
  float inv = lsum > 0.f ? 1.0f / lsum : 0.f;
  unsigned short* hrow = Hd + (size_t)(b * NQS + q) * 512 + hd * 64;
#pragma unroll
  for (int vt = 0; vt < 2; vt++) {
#pragma unroll
    for (int gr = 0; gr < 4; gr++) {
      ushort4 u;
      float v0 = (vt ? o1[gr * 4 + 0] : o0[gr * 4 + 0]) * inv;
      float v1 = (vt ? o1[gr * 4 + 1] : o0[gr * 4 + 1]) * inv;
      float v2 = (vt ? o1[gr * 4 + 2] : o0[gr * 4 + 2]) * inv;
      float v3 = (vt ? o1[gr * 4 + 3] : o0[gr * 4 + 3]) * inv;
      u.x = f2bf(v0); u.y = f2bf(v1); u.z = f2bf(v2); u.w = f2bf(v3);
      int vv = vt * 32 + 8 * gr + hi4;
      *(ushort4*)(hrow + vv) = u;
    }
  }
}

// ---------------- launch ----------------

extern "C" void kernel_launch(void* const* d_in, const int* in_sizes, int n_in,
                              void* d_out, int out_size, void* d_ws, size_t ws_size,
                              hipStream_t stream) {
  const float* q = (const float*)d_in[0];
  const float* h = (const float*)d_in[1];
  const void* mask = d_in[2];
  const float* wq = (const float*)d_in[3];
  const float* wk = (const float*)d_in[4];
  const float* wv = (const float*)d_in[5];
  const float* wo = (const float*)d_in[6];
  float* out = (float*)d_out;

  unsigned short* qb_ = (unsigned short*)d_ws;       // 8192*512 each
  unsigned short* hb_ = qb_ + 8192 * 512;
  unsigned short* Qp = hb_ + 8192 * 512;
  unsigned short* Kp = Qp + 8192 * 512;
  unsigned short* Vtp = Kp + 8192 * 512;             // transposed V: [(b*8+h)*64+v][2048]
  unsigned short* Hd = Vtp + 8192 * 512;
  unsigned short* wqt = Hd + 8192 * 512;
  unsigned short* wkvt = wqt + 512 * 512;            // [1024][512]
  unsigned short* wot = wkvt + 1024 * 512;
  unsigned short* maskB16 = wot + 512 * 512;         // 4*2048*128 u16 = 2 MB

  k_prep<<<3584, 256, 0, stream>>>((const float4*)q, (const float4*)h, mask, wq, wk, wv, wo,
                                   (ushort4*)qb_, (ushort4*)hb_, wqt, wkvt, wot, maskB16);
  dim3 gqkv(128, 12);
  k_gemmQKV<<<gqkv, 256, 0, stream>>>(qb_, hb_, wqt, wkvt, Qp, Kp, Vtp);
  k_attn7<<<512, 256, 0, stream>>>(Qp, Kp, Vtp, maskB16, Hd);
  dim3 go(128, 4);
  k_gemm3<1><<<go, 256, 0, stream>>>(Hd, wot, out, nullptr);
}

// Round 11
// 143.274 us; speedup vs baseline: 1.5268x; 1.5268x over previous
//
#include <hip/hip_runtime.h>
#include <hip/hip_bf16.h>
#include <stdint.h>

#define NHEADS 8
#define INDIM 512
#define EMB 512
#define BSZ 4
#define NQS 2048
#define GS 2048

// 0.125 * log2(e): folded into W_query so attention exp is a bare 2^x
#define ALPHA_F 0.18033688011112042f

#if __has_builtin(__builtin_amdgcn_exp2f)
#define EXP2(x) __builtin_amdgcn_exp2f(x)
#else
#define EXP2(x) __expf((x)*0.69314718056f)
#endif

typedef short bf16x8 __attribute__((ext_vector_type(8)));
typedef float f32x4 __attribute__((ext_vector_type(4)));
typedef float f32x16 __attribute__((ext_vector_type(16)));
typedef unsigned int u32x4 __attribute__((ext_vector_type(4)));

static __device__ __forceinline__ unsigned short f2bf(float f) {
  unsigned int u = __builtin_bit_cast(unsigned int, f);
  unsigned int rounding = 0x7FFFu + ((u >> 16) & 1u);
  u += rounding;
  return (unsigned short)(u >> 16);
}

typedef __attribute__((address_space(3))) void lds_void;
typedef __attribute__((address_space(1))) const void gm_void;
static __device__ __forceinline__ void gll16(const void* g, void* s) {
  __builtin_amdgcn_global_load_lds((gm_void*)g, (lds_void*)s, 16, 0, 0);
}

// ---------------- fused prep: cvt q,h + pack weights + bit-pack mask ----------------
__global__ void k_prep(const float4* __restrict__ q, const float4* __restrict__ h,
                       const void* __restrict__ mask,
                       const float* __restrict__ wq, const float* __restrict__ wk,
                       const float* __restrict__ wv, const float* __restrict__ wo,
                       ushort4* __restrict__ qb, ushort4* __restrict__ hb,
                       unsigned short* __restrict__ wqt, unsigned short* __restrict__ wkvt,
                       unsigned short* __restrict__ wot, unsigned short* __restrict__ maskB16) {
  int blk = blockIdx.x, t = threadIdx.x;
  if (blk < 2048) {
    const float4* src = blk < 1024 ? q : h;
    ushort4* dst = blk < 1024 ? qb : hb;
    int base = (blk & 1023) * 256 + t;
#pragma unroll
    for (int i = 0; i < 4; i++) {
      int idx = base + i * 262144;
      float4 v = src[idx];
      ushort4 o;
      o.x = f2bf(v.x); o.y = f2bf(v.y); o.z = f2bf(v.z); o.w = f2bf(v.w);
      dst[idx] = o;
    }
  } else if (blk < 3072) {
    const unsigned int* m32h = (const unsigned int*)mask;
    bool bytes = __ballot(m32h[t & 63] > 1u) != 0ull;
    int base = (blk - 2048) * 256 + t;
#pragma unroll
    for (int i = 0; i < 4; i++) {
      int widx = base + i * 262144;
      unsigned int bits = 0;
      if (bytes) {
        const uchar4* p = (const uchar4*)((const unsigned char*)mask + (size_t)widx * 16);
#pragma unroll
        for (int j = 0; j < 4; j++) {
          uchar4 v = p[j];
          bits |= ((v.x ? 1u : 0u) << (4 * j)) | ((v.y ? 1u : 0u) << (4 * j + 1)) |
                  ((v.z ? 1u : 0u) << (4 * j + 2)) | ((v.w ? 1u : 0u) << (4 * j + 3));
        }
      } else {
        const int4* p = (const int4*)((const int*)mask + (size_t)widx * 16);
#pragma unroll
        for (int j = 0; j < 4; j++) {
          int4 v = p[j];
          bits |= ((v.x ? 1u : 0u) << (4 * j)) | ((v.y ? 1u : 0u) << (4 * j + 1)) |
                  ((v.z ? 1u : 0u) << (4 * j + 2)) | ((v.w ? 1u : 0u) << (4 * j + 3));
        }
      }
      maskB16[widx] = (unsigned short)bits;
    }
  } else {
    int id = (blk - 3072) * 256 + t;
#pragma unroll
    for (int i = 0; i < 8; i++) {
      int e = id * 8 + i;
      int which = e >> 18, r = e & 262143;
      int k = r & 511, n = r >> 9;
      int hh = n >> 6, j = n & 63;
      if (which == 0) wqt[r] = f2bf(wq[hh * 32768 + k * 64 + j] * ALPHA_F);
      else if (which == 1) wkvt[r] = f2bf(wk[hh * 32768 + k * 64 + j]);
      else if (which == 2) wkvt[262144 + r] = f2bf(wv[hh * 32768 + k * 64 + j]);
      else wot[r] = f2bf(wo[k * 512 + n]);
    }
  }
}

// ---------------- out-proj GEMM (BM=64, BN=128, BK=64, counted prefetch) ----------------
template <int MODE>
__global__ __launch_bounds__(256) void k_gemm3(const unsigned short* __restrict__ A,
                                               const unsigned short* __restrict__ Bt,
                                               void* __restrict__ C, void* __restrict__ C2) {
  __shared__ unsigned short As[2][4096];
  __shared__ unsigned short Bs[2][8192];
  int m0 = blockIdx.x * 64, n0 = blockIdx.y * 128;
  int t = threadIdx.x;
  int w = t >> 6, l = t & 63, c = l & 15, lg = l >> 4;
  int wr = w >> 1, wc = w & 1;

  int rbA = t >> 7, kcc = (t >> 4) & 7, cc = t & 15;
  const unsigned short* aG = A + (size_t)(m0 + rbA * 16 + cc) * 512 + kcc * 8;
  const unsigned short* bG = Bt + (size_t)(n0 + rbA * 16 + cc) * 512 + kcc * 8;
  int ldsOff = w * 1024 + (t & 63) * 16;

  f32x4 acc[2][4];
#pragma unroll
  for (int mi = 0; mi < 2; mi++)
#pragma unroll
    for (int ni = 0; ni < 4; ni++) acc[mi][ni] = {0.f, 0.f, 0.f, 0.f};

  gll16(aG, (char*)As[0] + ldsOff);
  gll16(aG + 32 * 512, (char*)As[0] + ldsOff + 4096);
  gll16(bG, (char*)Bs[0] + ldsOff);
  gll16(bG + 32 * 512, (char*)Bs[0] + ldsOff + 4096);
  gll16(bG + 64 * 512, (char*)Bs[0] + ldsOff + 8192);
  gll16(bG + 96 * 512, (char*)Bs[0] + ldsOff + 12288);

  for (int kk = 0; kk < 8; kk++) {
    int cur = kk & 1;
    asm volatile("s_waitcnt vmcnt(0)" ::: "memory");
    __builtin_amdgcn_s_barrier();
    if (kk < 7) {
      int ko = (kk + 1) * 64;
      gll16(aG + ko, (char*)As[cur ^ 1] + ldsOff);
      gll16(aG + ko + 32 * 512, (char*)As[cur ^ 1] + ldsOff + 4096);
      gll16(bG + ko, (char*)Bs[cur ^ 1] + ldsOff);
      gll16(bG + ko + 32 * 512, (char*)Bs[cur ^ 1] + ldsOff + 4096);
      gll16(bG + ko + 64 * 512, (char*)Bs[cur ^ 1] + ldsOff + 8192);
      gll16(bG + ko + 96 * 512, (char*)Bs[cur ^ 1] + ldsOff + 12288);
    }
    bf16x8 af[2][2], bfr[4][2];
#pragma unroll
    for (int kc = 0; kc < 2; kc++) {
#pragma unroll
      for (int mi = 0; mi < 2; mi++)
        af[mi][kc] = *(const bf16x8*)((const char*)As[cur] + ((wr * 2 + mi) * 128 + (kc * 4 + lg) * 16 + c) * 16);
#pragma unroll
      for (int ni = 0; ni < 4; ni++)
        bfr[ni][kc] = *(const bf16x8*)((const char*)Bs[cur] + ((wc * 4 + ni) * 128 + (kc * 4 + lg) * 16 + c) * 16);
    }
#pragma unroll
    for (int kc = 0; kc < 2; kc++)
#pragma unroll
      for (int mi = 0; mi < 2; mi++)
#pragma unroll
        for (int ni = 0; ni < 4; ni++)
          acc[mi][ni] = __builtin_amdgcn_mfma_f32_16x16x32_bf16(af[mi][kc], bfr[ni][kc], acc[mi][ni], 0, 0, 0);
  }

#pragma unroll
  for (int mi = 0; mi < 2; mi++)
#pragma unroll
    for (int ni = 0; ni < 4; ni++) {
      int row = m0 + wr * 32 + mi * 16 + 4 * lg;
      int col = n0 + wc * 64 + ni * 16 + c;
#pragma unroll
      for (int r = 0; r < 4; r++)
        ((float*)C)[(size_t)(row + r) * 512 + col] = acc[mi][ni][r];
    }
}

// fused Q/K/V projection: grid (128, 12). y<4: Q -> Qp. y in [4,8): K -> Kp. [8,12): V -> Vt.
__global__ __launch_bounds__(256) void k_gemmQKV(const unsigned short* __restrict__ qb_,
                                                 const unsigned short* __restrict__ hb_,
                                                 const unsigned short* __restrict__ wqt,
                                                 const unsigned short* __restrict__ wkvt,
                                                 unsigned short* __restrict__ Qp,
                                                 unsigned short* __restrict__ Kp,
                                                 unsigned short* __restrict__ Vt) {
  __shared__ unsigned short As[2][4096];
  __shared__ unsigned short Bs[2][8192];
  int ny = blockIdx.y;
  const unsigned short* A = (ny < 4) ? qb_ : hb_;
  const unsigned short* Bt = (ny < 4) ? wqt : wkvt;
  int n0 = (ny < 4) ? ny * 128 : (ny - 4) * 128;
  int m0 = blockIdx.x * 64;
  int t = threadIdx.x;
  int w = t >> 6, l = t & 63, c = l & 15, lg = l >> 4;
  int wr = w >> 1, wc = w & 1;

  int rbA = t >> 7, kcc = (t >> 4) & 7, cc = t & 15;
  const unsigned short* aG = A + (size_t)(m0 + rbA * 16 + cc) * 512 + kcc * 8;
  const unsigned short* bG = Bt + (size_t)(n0 + rbA * 16 + cc) * 512 + kcc * 8;
  int ldsOff = w * 1024 + (t & 63) * 16;

  f32x4 acc[2][4];
#pragma unroll
  for (int mi = 0; mi < 2; mi++)
#pragma unroll
    for (int ni = 0; ni < 4; ni++) acc[mi][ni] = {0.f, 0.f, 0.f, 0.f};

  gll16(aG, (char*)As[0] + ldsOff);
  gll16(aG + 32 * 512, (char*)As[0] + ldsOff + 4096);
  gll16(bG, (char*)Bs[0] + ldsOff);
  gll16(bG + 32 * 512, (char*)Bs[0] + ldsOff + 4096);
  gll16(bG + 64 * 512, (char*)Bs[0] + ldsOff + 8192);
  gll16(bG + 96 * 512, (char*)Bs[0] + ldsOff + 12288);

  for (int kk = 0; kk < 8; kk++) {
    int cur = kk & 1;
    asm volatile("s_waitcnt vmcnt(0)" ::: "memory");
    __builtin_amdgcn_s_barrier();
    if (kk < 7) {
      int ko = (kk + 1) * 64;
      gll16(aG + ko, (char*)As[cur ^ 1] + ldsOff);
      gll16(aG + ko + 32 * 512, (char*)As[cur ^ 1] + ldsOff + 4096);
      gll16(bG + ko, (char*)Bs[cur ^ 1] + ldsOff);
      gll16(bG + ko + 32 * 512, (char*)Bs[cur ^ 1] + ldsOff + 4096);
      gll16(bG + ko + 64 * 512, (char*)Bs[cur ^ 1] + ldsOff + 8192);
      gll16(bG + ko + 96 * 512, (char*)Bs[cur ^ 1] + ldsOff + 12288);
    }
    bf16x8 af[2][2], bfr[4][2];
#pragma unroll
    for (int kc = 0; kc < 2; kc++) {
#pragma unroll
      for (int mi = 0; mi < 2; mi++)
        af[mi][kc] = *(const bf16x8*)((const char*)As[cur] + ((wr * 2 + mi) * 128 + (kc * 4 + lg) * 16 + c) * 16);
#pragma unroll
      for (int ni = 0; ni < 4; ni++)
        bfr[ni][kc] = *(const bf16x8*)((const char*)Bs[cur] + ((wc * 4 + ni) * 128 + (kc * 4 + lg) * 16 + c) * 16);
    }
#pragma unroll
    for (int kc = 0; kc < 2; kc++)
#pragma unroll
      for (int mi = 0; mi < 2; mi++)
#pragma unroll
        for (int ni = 0; ni < 4; ni++)
          acc[mi][ni] = __builtin_amdgcn_mfma_f32_16x16x32_bf16(af[mi][kc], bfr[ni][kc], acc[mi][ni], 0, 0, 0);
  }

#pragma unroll
  for (int mi = 0; mi < 2; mi++)
#pragma unroll
    for (int ni = 0; ni < 4; ni++) {
      int row = m0 + wr * 32 + mi * 16 + 4 * lg;
      int col = n0 + wc * 64 + ni * 16 + c;
      if (ny < 4) {
#pragma unroll
        for (int r = 0; r < 4; r++)
          Qp[(size_t)(row + r) * 512 + col] = f2bf(acc[mi][ni][r]);
      } else if (col < 512) {
#pragma unroll
        for (int r = 0; r < 4; r++)
          Kp[(size_t)(row + r) * 512 + col] = f2bf(acc[mi][ni][r]);
      } else {
        int col5 = col - 512, hd2 = col5 >> 6, vv = col5 & 63;
        int bb = row >> 11, g = row & 2047;
        ushort4 u;
        u.x = f2bf(acc[mi][ni][0]);
        u.y = f2bf(acc[mi][ni][1]);
        u.z = f2bf(acc[mi][ni][2]);
        u.w = f2bf(acc[mi][ni][3]);
        *(ushort4*)(Vt + (size_t)((bb * 8 + hd2) * 64 + vv) * GS + g) = u;
      }
    }
}

// ---------------- flash attention: 32x32x16, LDS-staged K/V, in-register P ----------------
// grid 512: fid = (bid&7)*64 + bid>>3 (XCD-bijective). qtile = fid&15 (128 q), bh = fid>>4.
// Lane owns q = qtile*128 + w*32 + (l&31). Swapped operands (verified R10):
//   S^T = K*Q^T; C map: col=l&31, row=(r&3)+8*(r>>2)+4*(l>>5)
//   P -> PV B-frags in-register via v_cvt_pk_bf16_f32 + v_permlane32_swap_b32 (verified R10)
// K/V staged via gll16 into fragment-linear LDS (lane-linear ds_read_b128), double-buffered;
// one vmcnt(0)+s_barrier per 64-g tile (attn4 sync structure). No P LDS, no lgkm full-stops.
// K chunk c (0..511): g2=c>>8, s=(c>>6)&3, l=c&63 -> src row g=kt*64+g2*32+(l&31), d=s*16+(l>>5)*8
// V chunk c (0..511): g2=c>>8, vb=(c>>7)&1, s2=(c>>6)&1, l=c&63 -> src row v=vb*32+(l&31), col g=kt*64+g2*32+s2*16+(l>>5)*8
__global__ __launch_bounds__(256, 2) void k_attn8(const unsigned short* __restrict__ Qp,
                                                  const unsigned short* __restrict__ Kp,
                                                  const unsigned short* __restrict__ Vt,
                                                  const unsigned short* __restrict__ maskB16,
                                                  unsigned short* __restrict__ Hd) {
  __shared__ unsigned short Ksh[2][4096];   // 8 KB per buffer (512 chunks x 16B)
  __shared__ unsigned short Vsh[2][4096];

  int bid = blockIdx.x;
  int fid = (bid & 7) * 64 + (bid >> 3);
  int qtile = fid & 15;
  int bh = fid >> 4;
  int b = bh >> 3, hd = bh & 7;

  int t = threadIdx.x;
  int w = t >> 6, l = t & 63;
  int lo = l & 31, hi = l >> 5, hi4 = hi * 4;
  int q = qtile * 128 + w * 32 + lo;

  // Q B-fragments (4 k-steps of 16 over d=64); row q, k = s*16 + hi*8 + j
  const unsigned short* qrow = Qp + (size_t)(b * NQS + q) * 512 + hd * 64 + hi * 8;
  bf16x8 qf[4];
#pragma unroll
  for (int s = 0; s < 4; s++) qf[s] = *(const bf16x8*)(qrow + s * 16);

  // staging source addrs for this thread's chunks c=t (g2=0) and c=t+256 (g2=1)
  const unsigned short* kg0 = Kp + (size_t)(b * GS + lo) * 512 + hd * 64 + w * 16 + hi * 8;
  int vbS = (t >> 7) & 1, s2S = (t >> 6) & 1;
  const unsigned short* vg0 = Vt + (size_t)(bh * 64 + vbS * 32 + lo) * GS + s2S * 16 + hi * 8;
  char* kd[2] = {(char*)Ksh[0] + w * 1024, (char*)Ksh[1] + w * 1024};
  char* vd[2] = {(char*)Vsh[0] + w * 1024, (char*)Vsh[1] + w * 1024};

  f32x16 o0, o1;
#pragma unroll
  for (int i = 0; i < 16; i++) { o0[i] = 0.f; o1[i] = 0.f; }
  float ls[4] = {0.f, 0.f, 0.f, 0.f};

  const unsigned long long* mrow = (const unsigned long long*)maskB16 + (size_t)(b * NQS + q) * 32;

  // prologue: stage tile 0 into buffer 0
  gll16(kg0, kd[0]);
  gll16(kg0 + 32 * 512, kd[0] + 4096);
  gll16(vg0, vd[0]);
  gll16(vg0 + 32, vd[0] + 4096);
  unsigned long long wm = mrow[0], wmn = 0;

  for (int kt = 0; kt < 32; kt++) {
    int cur = kt & 1;
    asm volatile("s_waitcnt vmcnt(0)" ::: "memory");  // tile-kt loads (issued last iter) landed
    __builtin_amdgcn_s_barrier();                     // all waves' loads landed; all done reading buf[cur^1]
    if (kt < 31) {
      const unsigned short* kg = kg0 + (size_t)(kt + 1) * 64 * 512;
      const unsigned short* vg = vg0 + (size_t)(kt + 1) * 64;
      gll16(kg, kd[cur ^ 1]);
      gll16(kg + 32 * 512, kd[cur ^ 1] + 4096);
      gll16(vg, vd[cur ^ 1]);
      gll16(vg + 32, vd[cur ^ 1] + 4096);
      wmn = mrow[kt + 1];
    }

#pragma unroll
    for (int g2 = 0; g2 < 2; g2++) {
      const unsigned short* Kc = (const unsigned short*)Ksh[cur] + g2 * 2048;
      // S^T = K * Q^T
      f32x16 sreg;
#pragma unroll
      for (int i = 0; i < 16; i++) sreg[i] = 0.f;
      __builtin_amdgcn_s_setprio(1);
#pragma unroll
      for (int s = 0; s < 4; s++) {
        bf16x8 ka = *(const bf16x8*)(Kc + (s * 64 + l) * 8);
        sreg = __builtin_amdgcn_mfma_f32_32x32x16_bf16(ka, qf[s], sreg, 0, 0, 0);
      }
      __builtin_amdgcn_s_setprio(0);
      // masked 2^s (lane-local)
      unsigned int mbits = (unsigned int)(wm >> (g2 * 32));
      float p[16];
#pragma unroll
      for (int r = 0; r < 16; r++) {
        float e = EXP2(sreg[r]);
        unsigned bit = (mbits >> ((r & 3) + 8 * (r >> 2) + hi4)) & 1u;
        p[r] = bit ? 0.f : e;
        ls[r & 3] += p[r];
      }
      // pack P -> bf16 PV B-fragments (cvt_pk + permlane32_swap; verified R10)
      unsigned int cw0, cw1, cw2, cw3, cw4, cw5, cw6, cw7;
      asm("v_cvt_pk_bf16_f32 %0, %1, %2" : "=v"(cw0) : "v"(p[0]), "v"(p[1]));
      asm("v_cvt_pk_bf16_f32 %0, %1, %2" : "=v"(cw1) : "v"(p[2]), "v"(p[3]));
      asm("v_cvt_pk_bf16_f32 %0, %1, %2" : "=v"(cw2) : "v"(p[4]), "v"(p[5]));
      asm("v_cvt_pk_bf16_f32 %0, %1, %2" : "=v"(cw3) : "v"(p[6]), "v"(p[7]));
      asm("v_cvt_pk_bf16_f32 %0, %1, %2" : "=v"(cw4) : "v"(p[8]), "v"(p[9]));
      asm("v_cvt_pk_bf16_f32 %0, %1, %2" : "=v"(cw5) : "v"(p[10]), "v"(p[11]));
      asm("v_cvt_pk_bf16_f32 %0, %1, %2" : "=v"(cw6) : "v"(p[12]), "v"(p[13]));
      asm("v_cvt_pk_bf16_f32 %0, %1, %2" : "=v"(cw7) : "v"(p[14]), "v"(p[15]));
      asm("v_permlane32_swap_b32 %0, %1" : "+v"(cw0), "+v"(cw2));
      asm("v_permlane32_swap_b32 %0, %1" : "+v"(cw1), "+v"(cw3));
      asm("v_permlane32_swap_b32 %0, %1" : "+v"(cw4), "+v"(cw6));
      asm("v_permlane32_swap_b32 %0, %1" : "+v"(cw5), "+v"(cw7));
      u32x4 pw0 = {cw0, cw1, cw2, cw3};
      u32x4 pw1 = {cw4, cw5, cw6, cw7};
      bf16x8 pb0 = __builtin_bit_cast(bf16x8, pw0);
      bf16x8 pb1 = __builtin_bit_cast(bf16x8, pw1);
      // O^T += V^T * P^T
      const unsigned short* Vc = (const unsigned short*)Vsh[cur] + g2 * 2048;
      bf16x8 va00 = *(const bf16x8*)(Vc + (0 * 64 + l) * 8);    // vb=0,s2=0
      bf16x8 va01 = *(const bf16x8*)(Vc + (1 * 64 + l) * 8);    // vb=0,s2=1
      bf16x8 va10 = *(const bf16x8*)(Vc + (2 * 64 + l) * 8);    // vb=1,s2=0
      bf16x8 va11 = *(const bf16x8*)(Vc + (3 * 64 + l) * 8);    // vb=1,s2=1
      __builtin_amdgcn_s_setprio(1);
      o0 = __builtin_amdgcn_mfma_f32_32x32x16_bf16(va00, pb0, o0, 0, 0, 0);
      o1 = __builtin_amdgcn_mfma_f32_32x32x16_bf16(va10, pb0, o1, 0, 0, 0);
      o0 = __builtin_amdgcn_mfma_f32_32x32x16_bf16(va01, pb1, o0, 0, 0, 0);
      o1 = __builtin_amdgcn_mfma_f32_32x32x16_bf16(va11, pb1, o1, 0, 0, 0);
      __builtin_amdgcn_s_setprio(0);
    }
    wm = wmn;
  }

  // epilogue: combine partner lane's l, normalize, store
  float lsum = (ls[0] + ls[1]) + (ls[2] + ls[3]);
  lsum += __shfl_xor(lsum, 32);
  float inv = lsum > 0.f ? 1.0f / lsum : 0.f;
  unsigned short* hrow = Hd + (size_t)(b * NQS + q) * 512 + hd * 64;
#pragma unroll
  for (int vt = 0; vt < 2; vt++) {
#pragma unroll
    for (int gr = 0; gr < 4; gr++) {
      ushort4 u;
      float v0 = (vt ? o1[gr * 4 + 0] : o0[gr * 4 + 0]) * inv;
      float v1 = (vt ? o1[gr * 4 + 1] : o0[gr * 4 + 1]) * inv;
      float v2 = (vt ? o1[gr * 4 + 2] : o0[gr * 4 + 2]) * inv;
      float v3 = (vt ? o1[gr * 4 + 3] : o0[gr * 4 + 3]) * inv;
      u.x = f2bf(v0); u.y = f2bf(v1); u.z = f2bf(v2); u.w = f2bf(v3);
      int vv = vt * 32 + 8 * gr + hi4;
      *(ushort4*)(hrow + vv) = u;
    }
  }
}

// ---------------- launch ----------------

extern "C" void kernel_launch(void* const* d_in, const int* in_sizes, int n_in,
                              void* d_out, int out_size, void* d_ws, size_t ws_size,
                              hipStream_t stream) {
  const float* q = (const float*)d_in[0];
  const float* h = (const float*)d_in[1];
  const void* mask = d_in[2];
  const float* wq = (const float*)d_in[3];
  const float* wk = (const float*)d_in[4];
  const float* wv = (const float*)d_in[5];
  const float* wo = (const float*)d_in[6];
  float* out = (float*)d_out;

  unsigned short* qb_ = (unsigned short*)d_ws;       // 8192*512 each
  unsigned short* hb_ = qb_ + 8192 * 512;
  unsigned short* Qp = hb_ + 8192 * 512;
  unsigned short* Kp = Qp + 8192 * 512;
  unsigned short* Vtp = Kp + 8192 * 512;             // transposed V: [(b*8+h)*64+v][2048]
  unsigned short* Hd = Vtp + 8192 * 512;
  unsigned short* wqt = Hd + 8192 * 512;
  unsigned short* wkvt = wqt + 512 * 512;            // [1024][512]
  unsigned short* wot = wkvt + 1024 * 512;
  unsigned short* maskB16 = wot + 512 * 512;         // 4*2048*128 u16 = 2 MB

  k_prep<<<3584, 256, 0, stream>>>((const float4*)q, (const float4*)h, mask, wq, wk, wv, wo,
                                   (ushort4*)qb_, (ushort4*)hb_, wqt, wkvt, wot, maskB16);
  dim3 gqkv(128, 12);
  k_gemmQKV<<<gqkv, 256, 0, stream>>>(qb_, hb_, wqt, wkvt, Qp, Kp, Vtp);
  k_attn8<<<512, 256, 0, stream>>>(Qp, Kp, Vtp, maskB16, Hd);
  dim3 go(128, 4);
  k_gemm3<1><<<go, 256, 0, stream>>>(Hd, wot, out, nullptr);
}